// Round 12
// baseline (10489.072 us; speedup 1.0000x reference)
//
#include <hip/hip_runtime.h>
#include <hip/hip_bf16.h>
#include <math.h>

#define B 64
#define T 2048
#define D 128
#define H 256
#define G 1024          // 4*H gate rows

// per-q packed weight sizes (in uint = f16-pairs)
#define L0_UINTS 49152   // 192 kpairs * 256 cols
#define L1_UINTS 65536   // 256 kpairs * 256 cols
#define PQ_UINTS (L0_UINTS + L1_UINTS)   // 114688 per q

#define L0_LDS 3         // LDS-resident kpair chunks, L0 kpairs 21..23
#define L1_LDS 14        // LDS-resident kpair chunks, L1 kpairs 18..31

typedef _Float16 h2v __attribute__((ext_vector_type(2)));
typedef float f2v __attribute__((ext_vector_type(2)));
typedef unsigned int u4v __attribute__((ext_vector_type(4)));

#if defined(__has_builtin)
#if __has_builtin(__builtin_amdgcn_fdot2)
#define HAS_FDOT2 1
#endif
#endif

__device__ __forceinline__ float dot2(unsigned int w, unsigned int h, float acc) {
#ifdef HAS_FDOT2
    return __builtin_amdgcn_fdot2(__builtin_bit_cast(h2v, w), __builtin_bit_cast(h2v, h), acc, false);
#else
    h2v wv = __builtin_bit_cast(h2v, w);
    h2v hv = __builtin_bit_cast(h2v, h);
    acc = fmaf((float)wv.x, (float)hv.x, acc);
    return fmaf((float)wv.y, (float)hv.y, acc);
#endif
}

__device__ __forceinline__ unsigned short f2h(float f) {
    _Float16 h = (_Float16)f;
    return __builtin_bit_cast(unsigned short, h);
}
__device__ __forceinline__ float h2f(unsigned short u) {
    return (float)__builtin_bit_cast(_Float16, u);
}
__device__ __forceinline__ unsigned int packh2(float a, float b) {
    return (unsigned int)f2h(a) | ((unsigned int)f2h(b) << 16);
}
__device__ __forceinline__ float sigm(float x) { return 1.0f / (1.0f + __expf(-x)); }
__device__ __forceinline__ float ftanh(float x) {
    x = fminf(fmaxf(x, -15.0f), 15.0f);
    float e = __expf(2.0f * x);
    return (e - 1.0f) / (e + 1.0f);
}

#define DOT4(w0, hp, a0, a1, a2, a3) \
    a0 = dot2(w0.x, hp, a0); a1 = dot2(w0.y, hp, a1); a2 = dot2(w0.z, hp, a2); a3 = dot2(w0.w, hp, a3);

// ---------------- prep ----------------
__global__ void k_zero(unsigned int* p, int n) {
    int i = blockIdx.x * blockDim.x + threadIdx.x;
    if (i < n) p[i] = 0u;
}

__global__ void k_bias_sum(const float* __restrict__ a, const float* __restrict__ b,
                           float* __restrict__ out, int n) {
    int i = blockIdx.x * blockDim.x + threadIdx.x;
    if (i < n) out[i] = a[i] + b[i];
}

// pack f32 weights -> f16 pairs, per-q column slices, k-major
__global__ void k_pack_w(const float* __restrict__ Wih0, const float* __restrict__ Whh0,
                         const float* __restrict__ Wih1, const float* __restrict__ Whh1,
                         unsigned int* __restrict__ PW) {
    int idx = blockIdx.x * blockDim.x + threadIdx.x;
    if (idx >= 4 * PQ_UINTS) return;
    int q = idx / PQ_UINTS;
    int off = idx % PQ_UINTS;
    float v0, v1;
    if (off < L0_UINTS) {
        int kp = off >> 8, c = off & 255;
        int gate = c >> 6, u = c & 63;
        int r = gate * 256 + q * 64 + u;
        int k = kp * 2;
        if (k < 128) { v0 = Wih0[(size_t)r * 128 + k];       v1 = Wih0[(size_t)r * 128 + k + 1]; }
        else         { v0 = Whh0[(size_t)r * 256 + k - 128]; v1 = Whh0[(size_t)r * 256 + k - 127]; }
    } else {
        int o2 = off - L0_UINTS;
        int kp = o2 >> 8, c = o2 & 255;
        int gate = c >> 6, u = c & 63;
        int r = gate * 256 + q * 64 + u;
        int k = kp * 2;
        if (k < 256) { v0 = Wih1[(size_t)r * 256 + k];       v1 = Wih1[(size_t)r * 256 + k + 1]; }
        else         { v0 = Whh1[(size_t)r * 256 + k - 256]; v1 = Whh1[(size_t)r * 256 + k - 255]; }
    }
    PW[idx] = packh2(v0, v1);
}

// ---------------- split fused 2-layer LSTM (round-7 structure + LDS 159.5 KB + T14) ----------------
// grid = 256 WGs: q = bid>>6, b = bid&63; 4 WGs per batch (same XCD).
// Streamed weights 320 KB/step from L2; 136 KB of weights LDS-resident.
// Exchange: packed-uint h stores -> D1 barrier (vmcnt drain) -> tid0 flag ->
// lane-0 flag poll per producer -> single data load. x(t+1) issued at loop
// top (T14), written to LDS in the tail.
__global__ __launch_bounds__(1024) void k_lstm_split(
    const float* __restrict__ x,        // B x T x D (f32)
    const unsigned int* __restrict__ PW,
    const float* __restrict__ bs0,      // G
    const float* __restrict__ bs1,      // G
    unsigned int* __restrict__ hxq,     // 2 x 4 x B x 64 uints (packed h0|h1 slices)
    unsigned int* __restrict__ flags,   // 4 x B x 64 uints (padded flag lines)
    unsigned int* __restrict__ seqo)    // B x T/8 x H x 4 uints
{
    __shared__ float s_gacc[8][512];         // 16384 B
    __shared__ float s_g[512];               // 2048 B
    __shared__ unsigned int s_k0p[192];      // [x pairs | h0 pairs]
    __shared__ unsigned int s_k1p[256];      // [h0 pairs | h1 pairs]
    __shared__ uint4 wl0[L0_LDS][512];       // 24576 B  (L0 kpairs 21..23)
    __shared__ uint4 wl1[L1_LDS][512];       // 114688 B (L1 kpairs 18..31)

    const int q   = blockIdx.x >> 6;
    const int b   = blockIdx.x & 63;
    const int tid = threadIdx.x;
    const int half = tid >> 9;          // 0 = L0 gemm, 1 = L1 gemm
    const int t2  = tid & 511;
    const int cg  = t2 & 63;            // 4-col group
    const int kb  = t2 >> 6;            // k-block 0..7

    const unsigned int* Wq = PW + (size_t)q * PQ_UINTS;
    const unsigned int* wbase =
        half == 0 ? (Wq + (size_t)(kb * 24) * 256 + 4 * cg)
                  : (Wq + L0_UINTS + (size_t)(kb * 32) * 256 + 4 * cg);

    // stage LDS-resident weight chunks (once)
    if (half == 0) {
        #pragma unroll
        for (int c = 0; c < L0_LDS; ++c)
            wl0[c][t2] = *(const uint4*)(wbase + (size_t)(21 + c) * 256);
    } else {
        #pragma unroll
        for (int c = 0; c < L1_LDS; ++c)
            wl1[c][t2] = *(const uint4*)(wbase + (size_t)(18 + c) * 256);
    }

    float bi0 = 0.f, bi1 = 0.f, bi2 = 0.f, bi3 = 0.f;
    if (tid < 64) {
        int u = q * 64 + tid;
        bi0 = bs0[u]; bi1 = bs0[256 + u]; bi2 = bs0[512 + u]; bi3 = bs0[768 + u];
    } else if (tid < 128) {
        int u = q * 64 + (tid - 64);
        bi0 = bs1[u]; bi1 = bs1[256 + u]; bi2 = bs1[512 + u]; bi3 = bs1[768 + u];
    }
    float c0 = 0.f, c1 = 0.f;
    unsigned int hb0 = 0u, hb1 = 0u, hb2 = 0u, hb3 = 0u;   // 8-step h1 f16 batch
    f2v xr = {0.f, 0.f};                                   // T14 prefetch register

    // prologue staging: zeros for h0(-1), h1(-2); x(0)
    if (tid < 128) s_k0p[64 + tid] = 0u;
    if (tid >= 128 && tid < 384) s_k1p[tid - 128] = 0u;
    if (tid >= 384 && tid < 448) {
        int i = tid - 384;
        f2v v = __builtin_nontemporal_load((const f2v*)(x + (size_t)b * T * D) + i);
        s_k0p[i] = packh2(v.x, v.y);
    }

    for (int t = 0; ; ++t) {
        __syncthreads();                               // A: staging + weights visible

        // T14: issue x(t+1) load early (wave 4); consumed in the tail
        if ((tid >> 6) == 4 && (t + 1) < T) {
            xr = __builtin_nontemporal_load(
                (const f2v*)(x + ((size_t)b * T + (t + 1)) * D) + (tid & 63));
        }

        // ---- gemm: L0 threads (cols 0..255), L1 threads (cols 256..511) ----
        if (half == 0) {
            if (t < T) {
                const unsigned int* sp = s_k0p + kb * 24;
                float a0 = 0.f, a1 = 0.f, a2 = 0.f, a3 = 0.f;
                #pragma unroll
                for (int i = 0; i < 5; ++i) {          // streamed kpairs 0..19
                    uint4 hp = *(const uint4*)(sp + 4 * i);
                    uint4 w0 = *(const uint4*)(wbase + (size_t)(4 * i + 0) * 256);
                    uint4 w1 = *(const uint4*)(wbase + (size_t)(4 * i + 1) * 256);
                    uint4 w2 = *(const uint4*)(wbase + (size_t)(4 * i + 2) * 256);
                    uint4 w3 = *(const uint4*)(wbase + (size_t)(4 * i + 3) * 256);
                    DOT4(w0, hp.x, a0, a1, a2, a3);
                    DOT4(w1, hp.y, a0, a1, a2, a3);
                    DOT4(w2, hp.z, a0, a1, a2, a3);
                    DOT4(w3, hp.w, a0, a1, a2, a3);
                }
                {                                      // kpair 20 (stream) + 21..23 (LDS)
                    uint4 hp = *(const uint4*)(sp + 20);
                    uint4 w20 = *(const uint4*)(wbase + (size_t)20 * 256);
                    DOT4(w20, hp.x, a0, a1, a2, a3);
                    uint4 wa = wl0[0][t2];
                    DOT4(wa, hp.y, a0, a1, a2, a3);
                    uint4 wb = wl0[1][t2];
                    DOT4(wb, hp.z, a0, a1, a2, a3);
                    uint4 wc = wl0[2][t2];
                    DOT4(wc, hp.w, a0, a1, a2, a3);
                }
                *(float4*)&s_gacc[kb][4 * cg] = make_float4(a0, a1, a2, a3);
            }
        } else {
            const unsigned int* sp = s_k1p + kb * 32;
            float a0 = 0.f, a1 = 0.f, a2 = 0.f, a3 = 0.f;
            #pragma unroll
            for (int i = 0; i < 4; ++i) {              // streamed kpairs 0..15
                uint4 hp = *(const uint4*)(sp + 4 * i);
                uint4 w0 = *(const uint4*)(wbase + (size_t)(4 * i + 0) * 256);
                uint4 w1 = *(const uint4*)(wbase + (size_t)(4 * i + 1) * 256);
                uint4 w2 = *(const uint4*)(wbase + (size_t)(4 * i + 2) * 256);
                uint4 w3 = *(const uint4*)(wbase + (size_t)(4 * i + 3) * 256);
                DOT4(w0, hp.x, a0, a1, a2, a3);
                DOT4(w1, hp.y, a0, a1, a2, a3);
                DOT4(w2, hp.z, a0, a1, a2, a3);
                DOT4(w3, hp.w, a0, a1, a2, a3);
            }
            {                                          // kpairs 16,17 (stream) + 18,19 (LDS)
                uint4 hp = *(const uint4*)(sp + 16);
                uint4 w16 = *(const uint4*)(wbase + (size_t)16 * 256);
                DOT4(w16, hp.x, a0, a1, a2, a3);
                uint4 w17 = *(const uint4*)(wbase + (size_t)17 * 256);
                DOT4(w17, hp.y, a0, a1, a2, a3);
                uint4 wa = wl1[0][t2];
                DOT4(wa, hp.z, a0, a1, a2, a3);
                uint4 wb = wl1[1][t2];
                DOT4(wb, hp.w, a0, a1, a2, a3);
            }
            #pragma unroll
            for (int g2 = 0; g2 < 3; ++g2) {           // kpairs 20..31 pure LDS
                uint4 hp = *(const uint4*)(sp + 20 + 4 * g2);
                uint4 w0 = wl1[2 + 4 * g2][t2];
                DOT4(w0, hp.x, a0, a1, a2, a3);
                uint4 w1 = wl1[3 + 4 * g2][t2];
                DOT4(w1, hp.y, a0, a1, a2, a3);
                uint4 w2 = wl1[4 + 4 * g2][t2];
                DOT4(w2, hp.z, a0, a1, a2, a3);
                uint4 w3 = wl1[5 + 4 * g2][t2];
                DOT4(w3, hp.w, a0, a1, a2, a3);
            }
            *(float4*)&s_gacc[kb][256 + 4 * cg] = make_float4(a0, a1, a2, a3);
        }
        __syncthreads();                               // B

        if (tid < 512) {
            float s = s_gacc[0][tid] + s_gacc[1][tid] + s_gacc[2][tid] + s_gacc[3][tid]
                    + s_gacc[4][tid] + s_gacc[5][tid] + s_gacc[6][tid] + s_gacc[7][tid];
            s_g[tid] = s;
        }
        __syncthreads();                               // C

        // ---- owners: nonlinearity + state + publish (packed, relaxed) ----
        if (tid < 64) {            // layer-0 unit q*64+tid -> h0(t)
            if (t < T) {
                int u = tid;
                float gi = s_g[u] + bi0;
                float gf = s_g[64 + u] + bi1;
                float gg = s_g[128 + u] + bi2;
                float go = s_g[192 + u] + bi3;
                c0 = sigm(gf) * c0 + sigm(gi) * ftanh(gg);
                float h0v = sigm(go) * ftanh(c0);
                float other = __shfl_xor(h0v, 1);
                if ((u & 1) == 0) {
                    __hip_atomic_store(hxq + ((((size_t)(t & 1) * 4 + q) * 64 + b) * 64) + (u >> 1),
                                       packh2(h0v, other), __ATOMIC_RELAXED, __HIP_MEMORY_SCOPE_AGENT);
                }
            }
        } else if (tid < 128) {    // layer-1 unit -> h1(t-1)
            int u = tid - 64;
            float h1v = 0.0f;
            if (t >= 1) {
                float gi = s_g[256 + u] + bi0;
                float gf = s_g[320 + u] + bi1;
                float gg = s_g[384 + u] + bi2;
                float go = s_g[448 + u] + bi3;
                c1 = sigm(gf) * c1 + sigm(gi) * ftanh(gg);
                h1v = sigm(go) * ftanh(c1);
                unsigned int hv = (unsigned int)f2h(h1v);
                int st = (t - 1) & 7;
                switch (st) {                          // uniform scalar branch
                    case 0: hb0 = hv; break;
                    case 1: hb0 |= hv << 16; break;
                    case 2: hb1 = hv; break;
                    case 3: hb1 |= hv << 16; break;
                    case 4: hb2 = hv; break;
                    case 5: hb2 |= hv << 16; break;
                    case 6: hb3 = hv; break;
                    default: hb3 |= hv << 16; break;
                }
                if (st == 7) {
                    size_t idx = ((size_t)b * (T / 8) + ((t - 1) >> 3)) * H + (q * 64 + u);
                    u4v val = {hb0, hb1, hb2, hb3};
                    __builtin_nontemporal_store(val, (u4v*)(seqo + idx * 4));
                }
            }
            if (t < T) {
                float other = __shfl_xor(h1v, 1);
                if ((u & 1) == 0) {
                    __hip_atomic_store(hxq + ((((size_t)(t & 1) * 4 + q) * 64 + b) * 64) + 32 + (u >> 1),
                                       packh2(h1v, other), __ATOMIC_RELAXED, __HIP_MEMORY_SCOPE_AGENT);
                }
            }
        }

        if (t == T) break;                             // uniform exit

        __syncthreads();                               // D1: stores drained (vmcnt0 at barrier)

        if (tid == 0) {
            __hip_atomic_store(flags + ((size_t)q * 64 + b) * 64, (unsigned)(t + 1),
                               __ATOMIC_RELAXED, __HIP_MEMORY_SCOPE_AGENT);
        }

        // ---- parallel per-producer poll + stage; wave 4 writes prefetched x ----
        {
            const int wv = tid >> 6, l = tid & 63;
            if (wv < 4) {
                unsigned f = 0;
                const unsigned int* fp = flags + ((size_t)wv * 64 + b) * 64;
                do {
                    if (l == 0) f = __hip_atomic_load(fp, __ATOMIC_RELAXED, __HIP_MEMORY_SCOPE_AGENT);
                    f = __shfl(f, 0);
                    if (f < (unsigned)(t + 1)) __builtin_amdgcn_s_sleep(1);
                } while (f < (unsigned)(t + 1));
                unsigned v = __hip_atomic_load(
                    hxq + ((((size_t)(t & 1) * 4 + wv) * 64 + b) * 64) + l,
                    __ATOMIC_RELAXED, __HIP_MEMORY_SCOPE_AGENT);
                if (l < 32) {
                    s_k0p[64 + wv * 32 + l] = v;
                    s_k1p[wv * 32 + l] = v;
                } else {
                    s_k1p[128 + wv * 32 + (l - 32)] = v;
                }
            } else if (wv == 4 && (t + 1) < T) {
                s_k0p[l] = packh2(xr.x, xr.y);          // T14 write-late
            }
        }
    }
}

// ---------------- attention (seqo: [B][T/8][H] x uint4 = 8 f16) ----------------
__global__ __launch_bounds__(256) void k_a2(const unsigned int* __restrict__ seq,
                                            const float* __restrict__ W2,
                                            float* __restrict__ a2out)
{
    __shared__ float s_hT[H];
    int b = blockIdx.x;
    int k = threadIdx.x;
    unsigned v = seq[(((size_t)b * (T / 8) + 255) * H + k) * 4 + 3];
    s_hT[k] = h2f((unsigned short)(v >> 16));
    __syncthreads();
    float acc = 0.f;
    #pragma unroll 4
    for (int h = 0; h < H; ++h) acc += s_hT[h] * W2[h * H + k];
    a2out[b * H + k] = acc;
}

__global__ __launch_bounds__(256) void k_scores(const unsigned int* __restrict__ seq,
                                                const float* __restrict__ W1,
                                                const float* __restrict__ a2,
                                                const float* __restrict__ attn_w,
                                                float* __restrict__ scores)
{
    const int RPB = 32;
    __shared__ float s_rows[RPB][H];
    __shared__ float s_part[RPB][4];
    int b   = blockIdx.y;
    int t0  = blockIdx.x * RPB;
    int tid = threadIdx.x;

    for (int it = tid; it < 4 * H; it += 256) {
        int tgi = it >> 8, h = it & 255;
        uint4 v = ((const uint4*)seq)[((size_t)b * (T / 8) + (t0 >> 3) + tgi) * H + h];
        int r0 = tgi * 8;
        s_rows[r0 + 0][h] = h2f((unsigned short)v.x);
        s_rows[r0 + 1][h] = h2f((unsigned short)(v.x >> 16));
        s_rows[r0 + 2][h] = h2f((unsigned short)v.y);
        s_rows[r0 + 3][h] = h2f((unsigned short)(v.y >> 16));
        s_rows[r0 + 4][h] = h2f((unsigned short)v.z);
        s_rows[r0 + 5][h] = h2f((unsigned short)(v.z >> 16));
        s_rows[r0 + 6][h] = h2f((unsigned short)v.w);
        s_rows[r0 + 7][h] = h2f((unsigned short)(v.w >> 16));
    }
    __syncthreads();

    int c = tid;
    float acc[RPB];
    #pragma unroll
    for (int r = 0; r < RPB; ++r) acc[r] = 0.f;
    for (int h = 0; h < H; ++h) {
        float w = W1[h * H + c];
        #pragma unroll
        for (int r = 0; r < RPB; ++r) acc[r] += s_rows[r][h] * w;
    }
    float a2v = a2[b * H + c];
    float wc  = attn_w[c];
    int lane = tid & 63, wv = tid >> 6;
    #pragma unroll
    for (int r = 0; r < RPB; ++r) {
        float v = ftanh(acc[r] + a2v) * wc;
        for (int off = 32; off; off >>= 1) v += __shfl_down(v, off);
        if (lane == 0) s_part[r][wv] = v;
    }
    __syncthreads();
    if (tid < RPB) {
        scores[(size_t)b * T + t0 + tid] =
            s_part[tid][0] + s_part[tid][1] + s_part[tid][2] + s_part[tid][3];
    }
}

__global__ __launch_bounds__(256) void k_finish(const unsigned int* __restrict__ seq,
                                                const float* __restrict__ scores,
                                                const float* __restrict__ gamma,
                                                const float* __restrict__ beta,
                                                float* __restrict__ out)
{
    __shared__ float s_p[T];
    __shared__ float s_red[4];
    const int b = blockIdx.x;
    const int tid = threadIdx.x;
    const int lane = tid & 63, wv = tid >> 6;

    const float* sc = scores + (size_t)b * T;
    float m = -1e30f;
    for (int t = tid; t < T; t += 256) m = fmaxf(m, sc[t]);
    for (int off = 32; off; off >>= 1) m = fmaxf(m, __shfl_down(m, off));
    if (lane == 0) s_red[wv] = m;
    __syncthreads();
    m = fmaxf(fmaxf(s_red[0], s_red[1]), fmaxf(s_red[2], s_red[3]));
    __syncthreads();

    float z = 0.f;
    for (int t = tid; t < T; t += 256) { float e = __expf(sc[t] - m); s_p[t] = e; z += e; }
    for (int off = 32; off; off >>= 1) z += __shfl_down(z, off);
    if (lane == 0) s_red[wv] = z;
    __syncthreads();
    z = s_red[0] + s_red[1] + s_red[2] + s_red[3];
    float rz = 1.0f / z;
    __syncthreads();

    const uint4* sq = (const uint4*)seq + (size_t)b * (T / 8) * H + tid;
    float ctx = 0.f;
    for (int tg = 0; tg < T / 8; ++tg) {
        uint4 v = sq[(size_t)tg * H];
        const float* pp = &s_p[tg * 8];
        ctx += pp[0] * h2f((unsigned short)v.x) + pp[1] * h2f((unsigned short)(v.x >> 16))
             + pp[2] * h2f((unsigned short)v.y) + pp[3] * h2f((unsigned short)(v.y >> 16))
             + pp[4] * h2f((unsigned short)v.z) + pp[5] * h2f((unsigned short)(v.z >> 16))
             + pp[6] * h2f((unsigned short)v.w) + pp[7] * h2f((unsigned short)(v.w >> 16));
    }
    ctx *= rz;

    float s1 = ctx;
    for (int off = 32; off; off >>= 1) s1 += __shfl_down(s1, off);
    if (lane == 0) s_red[wv] = s1;
    __syncthreads();
    float mu = (s_red[0] + s_red[1] + s_red[2] + s_red[3]) * (1.0f / H);
    __syncthreads();
    float dv = ctx - mu;
    float s2 = dv * dv;
    for (int off = 32; off; off >>= 1) s2 += __shfl_down(s2, off);
    if (lane == 0) s_red[wv] = s2;
    __syncthreads();
    float var = (s_red[0] + s_red[1] + s_red[2] + s_red[3]) * (1.0f / H);
    out[b * H + tid] = dv * rsqrtf(var + 1e-5f) * gamma[tid] + beta[tid];
}

// ---------------- host ----------------
extern "C" void kernel_launch(void* const* d_in, const int* in_sizes, int n_in,
                              void* d_out, int out_size, void* d_ws, size_t ws_size,
                              hipStream_t stream) {
    const float* x     = (const float*)d_in[0];
    const float* Wih0  = (const float*)d_in[1];
    const float* Whh0  = (const float*)d_in[2];
    const float* bih0  = (const float*)d_in[3];
    const float* bhh0  = (const float*)d_in[4];
    const float* Wih1  = (const float*)d_in[5];
    const float* Whh1  = (const float*)d_in[6];
    const float* bih1  = (const float*)d_in[7];
    const float* bhh1  = (const float*)d_in[8];
    const float* aW1   = (const float*)d_in[9];
    const float* aW2   = (const float*)d_in[10];
    const float* aw    = (const float*)d_in[11];
    const float* gamma = (const float*)d_in[12];
    const float* beta  = (const float*)d_in[13];
    float* out = (float*)d_out;

    // ---- workspace layout (bytes), ~66.5 MB ----
    char* base = (char*)d_ws;
    unsigned int* PW    = (unsigned int*)(base);            // 1,835,008 B
    float* bsum0        = (float*)(base + 1835008);         // 4096 B
    float* bsum1        = (float*)(base + 1839104);         // 4096 B
    unsigned int* flags = (unsigned int*)(base + 1843200);  // 65,536 B  (4x64 padded lines)
    unsigned int* hxq   = (unsigned int*)(base + 1908736);  // 131,072 B (2x4x64x64 uints)
    float* a2buf        = (float*)(base + 2039808);         // 65,536 B
    float* scoresb      = (float*)(base + 2105344);         // 524,288 B
    unsigned int* seqo  = (unsigned int*)(base + 2629632);  // 67,108,864 B (B x T/8 x H x uint4)

    k_zero<<<(4 * 64 * 64 + 255) / 256, 256, 0, stream>>>(flags, 4 * 64 * 64);
    k_pack_w<<<(4 * PQ_UINTS) / 256, 256, 0, stream>>>(Wih0, Whh0, Wih1, Whh1, PW);
    k_bias_sum<<<(G + 255) / 256, 256, 0, stream>>>(bih0, bhh0, bsum0, G);
    k_bias_sum<<<(G + 255) / 256, 256, 0, stream>>>(bih1, bhh1, bsum1, G);

    k_lstm_split<<<256, 1024, 0, stream>>>(x, PW, bsum0, bsum1, hxq, flags, seqo);

    k_a2<<<B, H, 0, stream>>>(seqo, aW2, a2buf);
    k_scores<<<dim3(T / 32, B), 256, 0, stream>>>(seqo, aW1, a2buf, aw, scoresb);
    k_finish<<<B, 256, 0, stream>>>(seqo, scoresb, gamma, beta, out);
}

// Round 13
// 7266.615 us; speedup vs baseline: 1.4435x; 1.4435x over previous
//
#include <hip/hip_runtime.h>
#include <hip/hip_bf16.h>
#include <math.h>

#define B 64
#define T 2048
#define D 128
#define H 256
#define G 1024          // 4*H gate rows

// per-q packed weight sizes (in uint = f16-pairs)
#define L0_UINTS 49152   // 192 kpairs * 256 cols
#define L1_UINTS 65536   // 256 kpairs * 256 cols
#define PQ_UINTS (L0_UINTS + L1_UINTS)   // 114688 per q

#define L0_RES 21        // resident kpairs per L0 thread (kpairs 0..20)
#define L1_RES 18        // resident kpairs per L1 thread (kpairs 0..17)
#define L0_LDS 3         // LDS kpairs 21..23
#define L1_LDS 14        // LDS kpairs 18..31

typedef _Float16 h2v __attribute__((ext_vector_type(2)));
typedef float f2v __attribute__((ext_vector_type(2)));
typedef unsigned int u4v __attribute__((ext_vector_type(4)));

#if defined(__has_builtin)
#if __has_builtin(__builtin_amdgcn_fdot2)
#define HAS_FDOT2 1
#endif
#endif

__device__ __forceinline__ float dot2(unsigned int w, unsigned int h, float acc) {
#ifdef HAS_FDOT2
    return __builtin_amdgcn_fdot2(__builtin_bit_cast(h2v, w), __builtin_bit_cast(h2v, h), acc, false);
#else
    h2v wv = __builtin_bit_cast(h2v, w);
    h2v hv = __builtin_bit_cast(h2v, h);
    acc = fmaf((float)wv.x, (float)hv.x, acc);
    return fmaf((float)wv.y, (float)hv.y, acc);
#endif
}

__device__ __forceinline__ unsigned short f2h(float f) {
    _Float16 h = (_Float16)f;
    return __builtin_bit_cast(unsigned short, h);
}
__device__ __forceinline__ float h2f(unsigned short u) {
    return (float)__builtin_bit_cast(_Float16, u);
}
__device__ __forceinline__ unsigned int packh2(float a, float b) {
    return (unsigned int)f2h(a) | ((unsigned int)f2h(b) << 16);
}
__device__ __forceinline__ float sigm(float x) { return 1.0f / (1.0f + __expf(-x)); }
__device__ __forceinline__ float ftanh(float x) {
    x = fminf(fmaxf(x, -15.0f), 15.0f);
    float e = __expf(2.0f * x);
    return (e - 1.0f) / (e + 1.0f);
}

// Pin a loaded uint4 into VGPRs: the asm "modifies" the value, so the
// compiler cannot rematerialize the load inside the loop (round-6/7
// post-mortem: this structure benched 0.36 ms faster than explicit
// in-loop streamed loads — keep it).
__device__ __forceinline__ void pin(uint4& w) {
    asm volatile("" : "+v"(w.x), "+v"(w.y), "+v"(w.z), "+v"(w.w));
}

#define DOT4(w0, hp, a0, a1, a2, a3) \
    a0 = dot2(w0.x, hp, a0); a1 = dot2(w0.y, hp, a1); a2 = dot2(w0.z, hp, a2); a3 = dot2(w0.w, hp, a3);

// ---------------- prep ----------------
__global__ void k_zero(unsigned int* p, int n) {
    int i = blockIdx.x * blockDim.x + threadIdx.x;
    if (i < n) p[i] = 0u;
}

__global__ void k_bias_sum(const float* __restrict__ a, const float* __restrict__ b,
                           float* __restrict__ out, int n) {
    int i = blockIdx.x * blockDim.x + threadIdx.x;
    if (i < n) out[i] = a[i] + b[i];
}

// pack f32 weights -> f16 pairs, per-q column slices, k-major
__global__ void k_pack_w(const float* __restrict__ Wih0, const float* __restrict__ Whh0,
                         const float* __restrict__ Wih1, const float* __restrict__ Whh1,
                         unsigned int* __restrict__ PW) {
    int idx = blockIdx.x * blockDim.x + threadIdx.x;
    if (idx >= 4 * PQ_UINTS) return;
    int q = idx / PQ_UINTS;
    int off = idx % PQ_UINTS;
    float v0, v1;
    if (off < L0_UINTS) {
        int kp = off >> 8, c = off & 255;
        int gate = c >> 6, u = c & 63;
        int r = gate * 256 + q * 64 + u;
        int k = kp * 2;
        if (k < 128) { v0 = Wih0[(size_t)r * 128 + k];       v1 = Wih0[(size_t)r * 128 + k + 1]; }
        else         { v0 = Whh0[(size_t)r * 256 + k - 128]; v1 = Whh0[(size_t)r * 256 + k - 127]; }
    } else {
        int o2 = off - L0_UINTS;
        int kp = o2 >> 8, c = o2 & 255;
        int gate = c >> 6, u = c & 63;
        int r = gate * 256 + q * 64 + u;
        int k = kp * 2;
        if (k < 256) { v0 = Wih1[(size_t)r * 256 + k];       v1 = Wih1[(size_t)r * 256 + k + 1]; }
        else         { v0 = Whh1[(size_t)r * 256 + k - 256]; v1 = Whh1[(size_t)r * 256 + k - 255]; }
    }
    PW[idx] = packh2(v0, v1);
}

// ---------------- split fused 2-layer LSTM (round-7 structure, +LDS residency) ----------------
// grid = 256 WGs: q = bid>>6, b = bid&63; 4 WGs per batch.
// wr[]/pin pre-loop weight loads (round-7-proven schedule) + 136 KB of
// weights LDS-resident -> streamed bytes 319 KB/WG/step. Exchange identical
// to round 7: packed-uint h stores -> D1 barrier -> tid0 flag -> lane-0
// flag poll -> single data load. x-load stays in the tail (wave 4),
// overlapped with other waves' polling.
__global__ __launch_bounds__(1024) void k_lstm_split(
    const float* __restrict__ x,        // B x T x D (f32)
    const unsigned int* __restrict__ PW,
    const float* __restrict__ bs0,      // G
    const float* __restrict__ bs1,      // G
    unsigned int* __restrict__ hxq,     // 2 x 4 x B x 64 uints (packed h0|h1 slices)
    unsigned int* __restrict__ flags,   // 4 x B x 64 uints (padded flag lines)
    unsigned int* __restrict__ seqo)    // B x T/8 x H x 4 uints
{
    __shared__ float s_gacc[8][512];         // 16384 B
    __shared__ float s_g[512];               // 2048 B
    __shared__ unsigned int s_k0p[192];      // [x pairs | h0 pairs]
    __shared__ unsigned int s_k1p[256];      // [h0 pairs | h1 pairs]
    __shared__ uint4 wl0[L0_LDS][512];       // 24576 B  (L0 kpairs 21..23)
    __shared__ uint4 wl1[L1_LDS][512];       // 114688 B (L1 kpairs 18..31)

    const int q   = blockIdx.x >> 6;
    const int b   = blockIdx.x & 63;
    const int tid = threadIdx.x;
    const int half = tid >> 9;          // 0 = L0 gemm, 1 = L1 gemm
    const int t2  = tid & 511;
    const int cg  = t2 & 63;            // 4-col group
    const int kb  = t2 >> 6;            // k-block 0..7

    const unsigned int* Wq = PW + (size_t)q * PQ_UINTS;
    const unsigned int* wbase =
        half == 0 ? (Wq + (size_t)(kb * 24) * 256 + 4 * cg)
                  : (Wq + L0_UINTS + (size_t)(kb * 32) * 256 + 4 * cg);

    // resident weight registers (pinned; round-7 structure)
    uint4 wr[L0_RES];
    if (half == 0) {
        #pragma unroll
        for (int i = 0; i < L0_RES; ++i) {
            wr[i] = *(const uint4*)(wbase + (size_t)i * 256);
            pin(wr[i]);
        }
        #pragma unroll
        for (int c = 0; c < L0_LDS; ++c)
            wl0[c][t2] = *(const uint4*)(wbase + (size_t)(L0_RES + c) * 256);
    } else {
        #pragma unroll
        for (int i = 0; i < L1_RES; ++i) {
            wr[i] = *(const uint4*)(wbase + (size_t)i * 256);
            pin(wr[i]);
        }
        #pragma unroll
        for (int c = 0; c < L1_LDS; ++c)
            wl1[c][t2] = *(const uint4*)(wbase + (size_t)(L1_RES + c) * 256);
    }

    float bi0 = 0.f, bi1 = 0.f, bi2 = 0.f, bi3 = 0.f;
    if (tid < 64) {
        int u = q * 64 + tid;
        bi0 = bs0[u]; bi1 = bs0[256 + u]; bi2 = bs0[512 + u]; bi3 = bs0[768 + u];
    } else if (tid < 128) {
        int u = q * 64 + (tid - 64);
        bi0 = bs1[u]; bi1 = bs1[256 + u]; bi2 = bs1[512 + u]; bi3 = bs1[768 + u];
    }
    float c0 = 0.f, c1 = 0.f;
    unsigned int hb0 = 0u, hb1 = 0u, hb2 = 0u, hb3 = 0u;   // 8-step h1 f16 batch

    // prologue staging: zeros for h0(-1), h1(-2); x(0)
    if (tid < 128) s_k0p[64 + tid] = 0u;
    if (tid >= 128 && tid < 384) s_k1p[tid - 128] = 0u;
    if (tid >= 384 && tid < 448) {
        int i = tid - 384;
        f2v v = __builtin_nontemporal_load((const f2v*)(x + (size_t)b * T * D) + i);
        s_k0p[i] = packh2(v.x, v.y);
    }

    for (int t = 0; ; ++t) {
        __syncthreads();                               // A: staging + weights visible

        // ---- gemm ----
        if (half == 0) {
            if (t < T) {
                const unsigned int* sp = s_k0p + kb * 24;
                float a0 = 0.f, a1 = 0.f, a2 = 0.f, a3 = 0.f;
                #pragma unroll
                for (int i = 0; i < 5; ++i) {          // resident kpairs 0..19
                    uint4 hp = *(const uint4*)(sp + 4 * i);
                    DOT4(wr[4 * i + 0], hp.x, a0, a1, a2, a3);
                    DOT4(wr[4 * i + 1], hp.y, a0, a1, a2, a3);
                    DOT4(wr[4 * i + 2], hp.z, a0, a1, a2, a3);
                    DOT4(wr[4 * i + 3], hp.w, a0, a1, a2, a3);
                }
                {                                      // kpair 20 (reg) + 21..23 (LDS)
                    uint4 hp = *(const uint4*)(sp + 20);
                    DOT4(wr[20], hp.x, a0, a1, a2, a3);
                    uint4 wa = wl0[0][t2];
                    DOT4(wa, hp.y, a0, a1, a2, a3);
                    uint4 wb = wl0[1][t2];
                    DOT4(wb, hp.z, a0, a1, a2, a3);
                    uint4 wc = wl0[2][t2];
                    DOT4(wc, hp.w, a0, a1, a2, a3);
                }
                *(float4*)&s_gacc[kb][4 * cg] = make_float4(a0, a1, a2, a3);
            }
        } else {
            const unsigned int* sp = s_k1p + kb * 32;
            float a0 = 0.f, a1 = 0.f, a2 = 0.f, a3 = 0.f;
            #pragma unroll
            for (int i = 0; i < 4; ++i) {              // resident kpairs 0..15
                uint4 hp = *(const uint4*)(sp + 4 * i);
                DOT4(wr[4 * i + 0], hp.x, a0, a1, a2, a3);
                DOT4(wr[4 * i + 1], hp.y, a0, a1, a2, a3);
                DOT4(wr[4 * i + 2], hp.z, a0, a1, a2, a3);
                DOT4(wr[4 * i + 3], hp.w, a0, a1, a2, a3);
            }
            {                                          // kpairs 16,17 (reg) + 18,19 (LDS)
                uint4 hp = *(const uint4*)(sp + 16);
                DOT4(wr[16], hp.x, a0, a1, a2, a3);
                DOT4(wr[17], hp.y, a0, a1, a2, a3);
                uint4 wa = wl1[0][t2];
                DOT4(wa, hp.z, a0, a1, a2, a3);
                uint4 wb = wl1[1][t2];
                DOT4(wb, hp.w, a0, a1, a2, a3);
            }
            #pragma unroll
            for (int g2 = 0; g2 < 3; ++g2) {           // kpairs 20..31 pure LDS
                uint4 hp = *(const uint4*)(sp + 20 + 4 * g2);
                uint4 w0 = wl1[2 + 4 * g2][t2];
                DOT4(w0, hp.x, a0, a1, a2, a3);
                uint4 w1 = wl1[3 + 4 * g2][t2];
                DOT4(w1, hp.y, a0, a1, a2, a3);
                uint4 w2 = wl1[4 + 4 * g2][t2];
                DOT4(w2, hp.z, a0, a1, a2, a3);
                uint4 w3 = wl1[5 + 4 * g2][t2];
                DOT4(w3, hp.w, a0, a1, a2, a3);
            }
            *(float4*)&s_gacc[kb][256 + 4 * cg] = make_float4(a0, a1, a2, a3);
        }
        __syncthreads();                               // B

        if (tid < 512) {
            float s = s_gacc[0][tid] + s_gacc[1][tid] + s_gacc[2][tid] + s_gacc[3][tid]
                    + s_gacc[4][tid] + s_gacc[5][tid] + s_gacc[6][tid] + s_gacc[7][tid];
            s_g[tid] = s;
        }
        __syncthreads();                               // C

        // ---- owners: nonlinearity + state update + publish (packed, relaxed) ----
        if (tid < 64) {            // layer-0 unit q*64+tid -> h0(t)
            if (t < T) {
                int u = tid;
                float gi = s_g[u] + bi0;
                float gf = s_g[64 + u] + bi1;
                float gg = s_g[128 + u] + bi2;
                float go = s_g[192 + u] + bi3;
                c0 = sigm(gf) * c0 + sigm(gi) * ftanh(gg);
                float h0v = sigm(go) * ftanh(c0);
                float other = __shfl_xor(h0v, 1);
                if ((u & 1) == 0) {
                    __hip_atomic_store(hxq + ((((size_t)(t & 1) * 4 + q) * 64 + b) * 64) + (u >> 1),
                                       packh2(h0v, other), __ATOMIC_RELAXED, __HIP_MEMORY_SCOPE_AGENT);
                }
            }
        } else if (tid < 128) {    // layer-1 unit -> h1(t-1)
            int u = tid - 64;
            float h1v = 0.0f;
            if (t >= 1) {
                float gi = s_g[256 + u] + bi0;
                float gf = s_g[320 + u] + bi1;
                float gg = s_g[384 + u] + bi2;
                float go = s_g[448 + u] + bi3;
                c1 = sigm(gf) * c1 + sigm(gi) * ftanh(gg);
                h1v = sigm(go) * ftanh(c1);
                unsigned int hv = (unsigned int)f2h(h1v);
                int st = (t - 1) & 7;
                switch (st) {                          // uniform scalar branch
                    case 0: hb0 = hv; break;
                    case 1: hb0 |= hv << 16; break;
                    case 2: hb1 = hv; break;
                    case 3: hb1 |= hv << 16; break;
                    case 4: hb2 = hv; break;
                    case 5: hb2 |= hv << 16; break;
                    case 6: hb3 = hv; break;
                    default: hb3 |= hv << 16; break;
                }
                if (st == 7) {
                    size_t idx = ((size_t)b * (T / 8) + ((t - 1) >> 3)) * H + (q * 64 + u);
                    u4v val = {hb0, hb1, hb2, hb3};
                    __builtin_nontemporal_store(val, (u4v*)(seqo + idx * 4));
                }
            }
            if (t < T) {
                float other = __shfl_xor(h1v, 1);
                if ((u & 1) == 0) {
                    __hip_atomic_store(hxq + ((((size_t)(t & 1) * 4 + q) * 64 + b) * 64) + 32 + (u >> 1),
                                       packh2(h1v, other), __ATOMIC_RELAXED, __HIP_MEMORY_SCOPE_AGENT);
                }
            }
        }

        if (t == T) break;                             // uniform exit

        __syncthreads();                               // D1: stores drained (vmcnt0 at barrier)

        if (tid == 0) {
            __hip_atomic_store(flags + ((size_t)q * 64 + b) * 64, (unsigned)(t + 1),
                               __ATOMIC_RELAXED, __HIP_MEMORY_SCOPE_AGENT);
        }

        // ---- parallel per-producer poll + stage; wave 4 prefetches x ----
        {
            const int wv = tid >> 6, l = tid & 63;
            if (wv < 4) {
                unsigned f = 0;
                const unsigned int* fp = flags + ((size_t)wv * 64 + b) * 64;
                do {
                    if (l == 0) f = __hip_atomic_load(fp, __ATOMIC_RELAXED, __HIP_MEMORY_SCOPE_AGENT);
                    f = __shfl(f, 0);
                    if (f < (unsigned)(t + 1)) __builtin_amdgcn_s_sleep(1);
                } while (f < (unsigned)(t + 1));
                unsigned v = __hip_atomic_load(
                    hxq + ((((size_t)(t & 1) * 4 + wv) * 64 + b) * 64) + l,
                    __ATOMIC_RELAXED, __HIP_MEMORY_SCOPE_AGENT);
                if (l < 32) {
                    s_k0p[64 + wv * 32 + l] = v;
                    s_k1p[wv * 32 + l] = v;
                } else {
                    s_k1p[128 + wv * 32 + (l - 32)] = v;
                }
            } else if (wv == 4) {
                if (t + 1 < T) {
                    f2v v = __builtin_nontemporal_load(
                        (const f2v*)(x + ((size_t)b * T + (t + 1)) * D) + l);
                    s_k0p[l] = packh2(v.x, v.y);
                }
            }
        }
    }
}

// ---------------- attention (seqo layout: [B][T/8][H] x uint4 = 8 f16 per (b,tg,h)) ----------------
__global__ __launch_bounds__(256) void k_a2(const unsigned int* __restrict__ seq,
                                            const float* __restrict__ W2,
                                            float* __restrict__ a2out)
{
    __shared__ float s_hT[H];
    int b = blockIdx.x;
    int k = threadIdx.x;
    unsigned v = seq[(((size_t)b * (T / 8) + 255) * H + k) * 4 + 3];
    s_hT[k] = h2f((unsigned short)(v >> 16));
    __syncthreads();
    float acc = 0.f;
    #pragma unroll 4
    for (int h = 0; h < H; ++h) acc += s_hT[h] * W2[h * H + k];
    a2out[b * H + k] = acc;
}

__global__ __launch_bounds__(256) void k_scores(const unsigned int* __restrict__ seq,
                                                const float* __restrict__ W1,
                                                const float* __restrict__ a2,
                                                const float* __restrict__ attn_w,
                                                float* __restrict__ scores)
{
    const int RPB = 32;
    __shared__ float s_rows[RPB][H];
    __shared__ float s_part[RPB][4];
    int b   = blockIdx.y;
    int t0  = blockIdx.x * RPB;
    int tid = threadIdx.x;

    for (int it = tid; it < 4 * H; it += 256) {
        int tgi = it >> 8, h = it & 255;
        uint4 v = ((const uint4*)seq)[((size_t)b * (T / 8) + (t0 >> 3) + tgi) * H + h];
        int r0 = tgi * 8;
        s_rows[r0 + 0][h] = h2f((unsigned short)v.x);
        s_rows[r0 + 1][h] = h2f((unsigned short)(v.x >> 16));
        s_rows[r0 + 2][h] = h2f((unsigned short)v.y);
        s_rows[r0 + 3][h] = h2f((unsigned short)(v.y >> 16));
        s_rows[r0 + 4][h] = h2f((unsigned short)v.z);
        s_rows[r0 + 5][h] = h2f((unsigned short)(v.z >> 16));
        s_rows[r0 + 6][h] = h2f((unsigned short)v.w);
        s_rows[r0 + 7][h] = h2f((unsigned short)(v.w >> 16));
    }
    __syncthreads();

    int c = tid;
    float acc[RPB];
    #pragma unroll
    for (int r = 0; r < RPB; ++r) acc[r] = 0.f;
    for (int h = 0; h < H; ++h) {
        float w = W1[h * H + c];
        #pragma unroll
        for (int r = 0; r < RPB; ++r) acc[r] += s_rows[r][h] * w;
    }
    float a2v = a2[b * H + c];
    float wc  = attn_w[c];
    int lane = tid & 63, wv = tid >> 6;
    #pragma unroll
    for (int r = 0; r < RPB; ++r) {
        float v = ftanh(acc[r] + a2v) * wc;
        for (int off = 32; off; off >>= 1) v += __shfl_down(v, off);
        if (lane == 0) s_part[r][wv] = v;
    }
    __syncthreads();
    if (tid < RPB) {
        scores[(size_t)b * T + t0 + tid] =
            s_part[tid][0] + s_part[tid][1] + s_part[tid][2] + s_part[tid][3];
    }
}

__global__ __launch_bounds__(256) void k_finish(const unsigned int* __restrict__ seq,
                                                const float* __restrict__ scores,
                                                const float* __restrict__ gamma,
                                                const float* __restrict__ beta,
                                                float* __restrict__ out)
{
    __shared__ float s_p[T];
    __shared__ float s_red[4];
    const int b = blockIdx.x;
    const int tid = threadIdx.x;
    const int lane = tid & 63, wv = tid >> 6;

    const float* sc = scores + (size_t)b * T;
    float m = -1e30f;
    for (int t = tid; t < T; t += 256) m = fmaxf(m, sc[t]);
    for (int off = 32; off; off >>= 1) m = fmaxf(m, __shfl_down(m, off));
    if (lane == 0) s_red[wv] = m;
    __syncthreads();
    m = fmaxf(fmaxf(s_red[0], s_red[1]), fmaxf(s_red[2], s_red[3]));
    __syncthreads();

    float z = 0.f;
    for (int t = tid; t < T; t += 256) { float e = __expf(sc[t] - m); s_p[t] = e; z += e; }
    for (int off = 32; off; off >>= 1) z += __shfl_down(z, off);
    if (lane == 0) s_red[wv] = z;
    __syncthreads();
    z = s_red[0] + s_red[1] + s_red[2] + s_red[3];
    float rz = 1.0f / z;
    __syncthreads();

    const uint4* sq = (const uint4*)seq + (size_t)b * (T / 8) * H + tid;
    float ctx = 0.f;
    for (int tg = 0; tg < T / 8; ++tg) {
        uint4 v = sq[(size_t)tg * H];
        const float* pp = &s_p[tg * 8];
        ctx += pp[0] * h2f((unsigned short)v.x) + pp[1] * h2f((unsigned short)(v.x >> 16))
             + pp[2] * h2f((unsigned short)v.y) + pp[3] * h2f((unsigned short)(v.y >> 16))
             + pp[4] * h2f((unsigned short)v.z) + pp[5] * h2f((unsigned short)(v.z >> 16))
             + pp[6] * h2f((unsigned short)v.w) + pp[7] * h2f((unsigned short)(v.w >> 16));
    }
    ctx *= rz;

    float s1 = ctx;
    for (int off = 32; off; off >>= 1) s1 += __shfl_down(s1, off);
    if (lane == 0) s_red[wv] = s1;
    __syncthreads();
    float mu = (s_red[0] + s_red[1] + s_red[2] + s_red[3]) * (1.0f / H);
    __syncthreads();
    float dv = ctx - mu;
    float s2 = dv * dv;
    for (int off = 32; off; off >>= 1) s2 += __shfl_down(s2, off);
    if (lane == 0) s_red[wv] = s2;
    __syncthreads();
    float var = (s_red[0] + s_red[1] + s_red[2] + s_red[3]) * (1.0f / H);
    out[b * H + tid] = dv * rsqrtf(var + 1e-5f) * gamma[tid] + beta[tid];
}

// ---------------- host ----------------
extern "C" void kernel_launch(void* const* d_in, const int* in_sizes, int n_in,
                              void* d_out, int out_size, void* d_ws, size_t ws_size,
                              hipStream_t stream) {
    const float* x     = (const float*)d_in[0];
    const float* Wih0  = (const float*)d_in[1];
    const float* Whh0  = (const float*)d_in[2];
    const float* bih0  = (const float*)d_in[3];
    const float* bhh0  = (const float*)d_in[4];
    const float* Wih1  = (const float*)d_in[5];
    const float* Whh1  = (const float*)d_in[6];
    const float* bih1  = (const float*)d_in[7];
    const float* bhh1  = (const float*)d_in[8];
    const float* aW1   = (const float*)d_in[9];
    const float* aW2   = (const float*)d_in[10];
    const float* aw    = (const float*)d_in[11];
    const float* gamma = (const float*)d_in[12];
    const float* beta  = (const float*)d_in[13];
    float* out = (float*)d_out;

    // ---- workspace layout (bytes), ~66.5 MB ----
    char* base = (char*)d_ws;
    unsigned int* PW    = (unsigned int*)(base);            // 1,835,008 B
    float* bsum0        = (float*)(base + 1835008);         // 4096 B
    float* bsum1        = (float*)(base + 1839104);         // 4096 B
    unsigned int* flags = (unsigned int*)(base + 1843200);  // 65,536 B  (4x64 padded lines)
    unsigned int* hxq   = (unsigned int*)(base + 1908736);  // 131,072 B (2x4x64x64 uints)
    float* a2buf        = (float*)(base + 2039808);         // 65,536 B
    float* scoresb      = (float*)(base + 2105344);         // 524,288 B
    unsigned int* seqo  = (unsigned int*)(base + 2629632);  // 67,108,864 B (B x T/8 x H x uint4)

    k_zero<<<(4 * 64 * 64 + 255) / 256, 256, 0, stream>>>(flags, 4 * 64 * 64);
    k_pack_w<<<(4 * PQ_UINTS) / 256, 256, 0, stream>>>(Wih0, Whh0, Wih1, Whh1, PW);
    k_bias_sum<<<(G + 255) / 256, 256, 0, stream>>>(bih0, bhh0, bsum0, G);
    k_bias_sum<<<(G + 255) / 256, 256, 0, stream>>>(bih1, bhh1, bsum1, G);

    k_lstm_split<<<256, 1024, 0, stream>>>(x, PW, bsum0, bsum1, hxq, flags, seqo);

    k_a2<<<B, H, 0, stream>>>(seqo, aW2, a2buf);
    k_scores<<<dim3(T / 32, B), 256, 0, stream>>>(seqo, aW1, a2buf, aw, scoresb);
    k_finish<<<B, 256, 0, stream>>>(seqo, scoresb, gamma, beta, out);
}